// Round 7
// baseline (391.175 us; speedup 1.0000x reference)
//
#include <hip/hip_runtime.h>
#include <stdint.h>
#include <stddef.h>

// ---------- types ----------
typedef __bf16 bf16;
typedef __bf16 bf16x8 __attribute__((ext_vector_type(8)));
typedef __bf16 bf16x4 __attribute__((ext_vector_type(4)));
typedef float  f32x4  __attribute__((ext_vector_type(4)));
typedef float  f32x16 __attribute__((ext_vector_type(16)));
typedef unsigned short ush;
typedef ush ush8 __attribute__((ext_vector_type(8)));
typedef unsigned int uint;

// ---------- problem sizes ----------
#define B_  4
#define S_  2048
#define E_  1024
#define H_  16
#define D_  64
#define M_  (B_*S_)      // 8192 rows
#define K_  E_           // 1024 reduction
// 0.125 (1/sqrt(D)) * log2(e): QKV epilogue folds this into Q -> softmax in exp2 domain
#define QSCALE 0.18033688011112042f

// ---------- helpers ----------
__device__ __forceinline__ void gload_lds16(const void* g, void* l) {
  __builtin_amdgcn_global_load_lds((const __attribute__((address_space(1))) void*)g,
                                   (__attribute__((address_space(3))) void*)l, 16, 0, 0);
}
__device__ __forceinline__ f32x4 mfma16(bf16x8 a, bf16x8 b, f32x4 c) {
  return __builtin_amdgcn_mfma_f32_16x16x32_bf16(a, b, c, 0, 0, 0);
}
__device__ __forceinline__ f32x16 mfma32(bf16x8 a, bf16x8 b, f32x16 c) {
  return __builtin_amdgcn_mfma_f32_32x32x16_bf16(a, b, c, 0, 0, 0);
}
__device__ __forceinline__ int swz4(int row, int ch) { return ch ^ ((row >> 1) & 3); }
__device__ __forceinline__ uint cvtpk(float lo, float hi) {
  uint r;
  asm("v_cvt_pk_bf16_f32 %0, %1, %2" : "=v"(r) : "v"(lo), "v"(hi));
  return r;
}

// ---------- prep kernels ----------
__global__ void cast_f32_bf16(const float* __restrict__ src, bf16* __restrict__ dst, int n4) {
  int idx = blockIdx.x * blockDim.x + threadIdx.x;
  int stride = gridDim.x * blockDim.x;
  for (int i = idx; i < n4; i += stride) {
    float4 v = ((const float4*)src)[i];
    union { bf16 b[4]; ushort4 u; } cv;
    cv.b[0] = (bf16)v.x; cv.b[1] = (bf16)v.y; cv.b[2] = (bf16)v.z; cv.b[3] = (bf16)v.w;
    ((ushort4*)dst)[i] = cv.u;
  }
}

// pack Wq|Wk|Wv [H,E,D] -> Wp[n][e], n = which*1024 + h*64 + d. LDS-tiled transpose.
__global__ void pack_w_t(const float* __restrict__ Wq, const float* __restrict__ Wk,
                         const float* __restrict__ Wv, bf16* __restrict__ Wp) {
  __shared__ float t[64][65];
  const int tid = threadIdx.x;
  const int wh = blockIdx.y;          // 0..47
  const int which = wh >> 4, h = wh & 15;
  const int e0 = blockIdx.x << 6;
  const float* src = (which == 0) ? Wq : (which == 1 ? Wk : Wv);
  src += (size_t)h * (E_ * D_);       // [E][D] for this head
  #pragma unroll
  for (int i = 0; i < 4; ++i) {
    int fi = tid + 256 * i;
    int e = fi >> 4, c = fi & 15;
    float4 v = *(const float4*)(src + (size_t)(e0 + e) * D_ + c * 4);
    t[c * 4 + 0][e] = v.x; t[c * 4 + 1][e] = v.y;
    t[c * 4 + 2][e] = v.z; t[c * 4 + 3][e] = v.w;
  }
  __syncthreads();
  #pragma unroll
  for (int i = 0; i < 2; ++i) {
    int cid = tid + 256 * i;
    int d = cid >> 3, cc = cid & 7;
    ush8 o;
    #pragma unroll
    for (int j = 0; j < 8; ++j) {
      union { bf16 b; ush u; } cv; cv.b = (bf16)t[d][cc * 8 + j]; o[j] = cv.u;
    }
    *(ush8*)(Wp + ((size_t)which * 1024 + h * 64 + d) * K_ + e0 + cc * 8) = o;
  }
}

// ---------- GEMM: C[M][N] = A[M][K] * Bm[N][K]^T ----------
template <int MODE>
__launch_bounds__(256, 2)
__global__ void gemm_kernel(const bf16* __restrict__ A, const bf16* __restrict__ Bm,
                            int Ntot,
                            const float* __restrict__ bias0, const float* __restrict__ bias1,
                            const float* __restrict__ bias2,
                            bf16* __restrict__ Qo, bf16* __restrict__ Ko, bf16* __restrict__ Vo,
                            float* __restrict__ Fo) {
  __shared__ __align__(16) bf16 lds_a[2][128 * 32];
  __shared__ __align__(16) bf16 lds_b[2][128 * 32];
  const int tid = threadIdx.x;
  const int lane = tid & 63;
  const int w = tid >> 6;
  const int wr = w >> 1, wc = w & 1;
  const int nblk = Ntot >> 7;
  const int mt = blockIdx.x / nblk, nt = blockIdx.x % nblk;
  const int m0 = mt << 7, n0 = nt << 7;

  f32x4 acc[4][4] = {};

  auto stage = [&](int buf, int kt) {
    #pragma unroll
    for (int i = 0; i < 2; ++i) {
      int cb = (w * 2 + i) * 64;
      int cid = cb + lane;
      int row = cid >> 2, cir = cid & 3;
      int lch = swz4(row, cir);
      const bf16* ga = A  + (size_t)(m0 + row) * K_ + kt * 32 + lch * 8;
      const bf16* gb = Bm + (size_t)(n0 + row) * K_ + kt * 32 + lch * 8;
      gload_lds16(ga, &lds_a[buf][cb * 8]);
      gload_lds16(gb, &lds_b[buf][cb * 8]);
    }
  };

  const int NT = K_ / 32;
  stage(0, 0);
  for (int kt = 0; kt < NT; ++kt) {
    if (kt + 1 < NT) stage((kt + 1) & 1, kt + 1);
    __syncthreads();
    const bf16x8* pa = (const bf16x8*)&lds_a[kt & 1][0];
    const bf16x8* pb = (const bf16x8*)&lds_b[kt & 1][0];
    bf16x8 af[4], bfr[4];
    #pragma unroll
    for (int mb = 0; mb < 4; ++mb) {
      int row = wr * 64 + mb * 16 + (lane & 15);
      af[mb] = pa[row * 4 + swz4(row, lane >> 4)];
    }
    #pragma unroll
    for (int nb = 0; nb < 4; ++nb) {
      int row = wc * 64 + nb * 16 + (lane & 15);
      bfr[nb] = pb[row * 4 + swz4(row, lane >> 4)];
    }
    #pragma unroll
    for (int mb = 0; mb < 4; ++mb)
      #pragma unroll
      for (int nb = 0; nb < 4; ++nb)
        acc[mb][nb] = mfma16(af[mb], bfr[nb], acc[mb][nb]);
    __syncthreads();
  }

  #pragma unroll
  for (int mb = 0; mb < 4; ++mb) {
    #pragma unroll
    for (int nb = 0; nb < 4; ++nb) {
      #pragma unroll
      for (int r = 0; r < 4; ++r) {
        int mi = m0 + wr * 64 + mb * 16 + (lane >> 4) * 4 + r;
        int ni = n0 + wc * 64 + nb * 16 + (lane & 15);
        float v = acc[mb][nb][r];
        if (MODE == 0) {
          int which = ni >> 10;
          int col = ni & 1023;
          const float* bp = (which == 0) ? bias0 : (which == 1 ? bias1 : bias2);
          v += bp[col];
          if (which == 0) v *= QSCALE;   // fold 1/sqrt(D)*log2e into Q
          int h = col >> 6, d = col & 63;
          int b = mi >> 11, s = mi & 2047;
          bf16* dst = (which == 0) ? Qo : (which == 1 ? Ko : Vo);
          dst[(((size_t)(b * H_ + h)) * S_ + s) * D_ + d] = (bf16)v;
        } else {
          Fo[(size_t)mi * E_ + ni] = v + bias0[ni];
        }
      }
    }
  }
}

// ---------- V transpose: V[B,H,S,D] -> Vt[B,H,D,S] ----------
__global__ void transpose_v(const bf16* __restrict__ V, bf16* __restrict__ Vt) {
  __shared__ ush t[64 * 65];
  const int bh = blockIdx.y;
  const int s0 = blockIdx.x * 64;
  const int tid = threadIdx.x;
  #pragma unroll
  for (int i = 0; i < 2; ++i) {
    int cid = tid + 256 * i;
    int r = cid >> 3, c = cid & 7;
    ush8 val = *(const ush8*)(V + ((size_t)bh * S_ + s0 + r) * D_ + c * 8);
    #pragma unroll
    for (int j = 0; j < 8; ++j) t[(c * 8 + j) * 65 + r] = val[j];
  }
  __syncthreads();
  #pragma unroll
  for (int i = 0; i < 2; ++i) {
    int cid = tid + 256 * i;
    int d = cid >> 3, sc = cid & 7;
    ush8 o;
    #pragma unroll
    for (int j = 0; j < 8; ++j) o[j] = t[d * 65 + sc * 8 + j];
    *(ush8*)(Vt + ((size_t)bh * D_ + d) * S_ + s0 + sc * 8) = o;
  }
}

// ---------- flash attention (causal): kv-parity split + register double-buffer ----------
// Block = one 32-row q-unit, 2 waves: wave w takes kv tiles t == w (mod 2), each with
// its own online-softmax state; one LDS merge at the end. No barriers in the kv loop.
// Each wave prefetches tile t+2's K/V fragments into a second named register set
// (fA/fB, statically indexed) BEFORE computing tile t -> L2 latency hides under compute.
struct QTile {
  bf16x8 qf[4];
  f32x16 oacc[2];
  float m, l;
};
struct KVf {
  bf16x8 k0[4], k1[4];   // K rows ln, ln+32
  bf16x8 v0[4], v1[4];   // Vt rows ln, 32+ln
};

__device__ __forceinline__ void init_q(QTile& S, const bf16* qrow, int hi) {
  #pragma unroll
  for (int kc = 0; kc < 4; ++kc)
    S.qf[kc] = *(const bf16x8*)(qrow + (2 * kc + hi) * 8);
  #pragma unroll
  for (int r = 0; r < 16; ++r) { S.oacc[0][r] = 0.f; S.oacc[1][r] = 0.f; }
  S.m = -1e30f; S.l = 0.f;
}

__device__ __forceinline__ void load_kv(KVf& F, const bf16* __restrict__ Kb,
                                        const bf16* __restrict__ Vb,
                                        int kv0, int hi, int ln) {
  const bf16* kr0 = Kb + (size_t)(kv0 + ln) * D_;
  const bf16* kr1 = Kb + (size_t)(kv0 + 32 + ln) * D_;
  #pragma unroll
  for (int kc = 0; kc < 4; ++kc) {
    F.k0[kc] = *(const bf16x8*)(kr0 + (2 * kc + hi) * 8);
    F.k1[kc] = *(const bf16x8*)(kr1 + (2 * kc + hi) * 8);
  }
  const bf16* vr0 = Vb + (size_t)ln * S_ + kv0;
  const bf16* vr1 = Vb + (size_t)(32 + ln) * S_ + kv0;
  #pragma unroll
  for (int ks = 0; ks < 4; ++ks) {
    F.v0[ks] = *(const bf16x8*)(vr0 + (2 * ks + hi) * 8);
    F.v1[ks] = *(const bf16x8*)(vr1 + (2 * ks + hi) * 8);
  }
}

__device__ __forceinline__ void compute_kv(QTile& S, const KVf& F,
                                           int kv0, int qu, int qg_, int hi, int ln) {
  // ---- QK^T (S^T = mfma(K, Q)): lane owns q=ln; kv regs crow(r,hi) ----
  f32x16 s0 = {}, s1 = {};
  __builtin_amdgcn_s_setprio(1);
  #pragma unroll
  for (int kc = 0; kc < 4; ++kc) {
    s0 = mfma32(F.k0[kc], S.qf[kc], s0);
    s1 = mfma32(F.k1[kc], S.qf[kc], s1);
  }
  __builtin_amdgcn_s_setprio(0);
  // causal mask (only the diagonal-touching tile)
  if (kv0 + 63 > qu) {
    #pragma unroll
    for (int r = 0; r < 16; ++r) {
      int crow = (r & 3) + 8 * (r >> 2) + 4 * hi;
      if (kv0 + crow > qg_)      s0[r] = -1e30f;
      if (kv0 + 32 + crow > qg_) s1[r] = -1e30f;
    }
  }
  // ---- online softmax, lane-local (exp2 domain) ----
  float mt_ = s0[0];
  #pragma unroll
  for (int r = 1; r < 16; ++r) mt_ = fmaxf(mt_, s0[r]);
  #pragma unroll
  for (int r = 0; r < 16; ++r) mt_ = fmaxf(mt_, s1[r]);
  mt_ = fmaxf(mt_, __shfl_xor(mt_, 32, 64));
  bool resc = mt_ > S.m + 8.f;          // defer-max (T13)
  float mnew = resc ? mt_ : S.m;
  float alpha = resc ? exp2f(S.m - mnew) : 1.f;
  S.m = mnew;
  float rs = 0.f;
  #pragma unroll
  for (int r = 0; r < 16; ++r) { float p = exp2f(s0[r] - mnew); s0[r] = p; rs += p; }
  #pragma unroll
  for (int r = 0; r < 16; ++r) { float p = exp2f(s1[r] - mnew); s1[r] = p; rs += p; }
  rs += __shfl_xor(rs, 32, 64);
  S.l = S.l * alpha + rs;
  if (__any(resc)) {
    #pragma unroll
    for (int r = 0; r < 16; ++r) { S.oacc[0][r] *= alpha; S.oacc[1][r] *= alpha; }
  }
  // ---- pack P -> PV B-fragments (cvt_pk + permlane32_swap, T12) ----
  bf16x8 pf[4];
  #pragma unroll
  for (int mtl = 0; mtl < 2; ++mtl) {
    #pragma unroll
    for (int c = 0; c < 2; ++c) {
      const f32x16& p = mtl ? s1 : s0;
      uint wa = cvtpk(p[8 * c + 0], p[8 * c + 1]);
      uint wb = cvtpk(p[8 * c + 2], p[8 * c + 3]);
      uint wcx = cvtpk(p[8 * c + 4], p[8 * c + 5]);
      uint wd = cvtpk(p[8 * c + 6], p[8 * c + 7]);
      asm("v_permlane32_swap_b32 %0, %1" : "+v"(wa), "+v"(wcx));
      asm("v_permlane32_swap_b32 %0, %1" : "+v"(wb), "+v"(wd));
      union { uint u[4]; bf16x8 v; } cvt;
      cvt.u[0] = wa; cvt.u[1] = wb; cvt.u[2] = wcx; cvt.u[3] = wd;
      pf[mtl * 2 + c] = cvt.v;
    }
  }
  // ---- O^T += Vt * P^T ----
  __builtin_amdgcn_s_setprio(1);
  #pragma unroll
  for (int ks = 0; ks < 4; ++ks) {
    S.oacc[0] = mfma32(F.v0[ks], pf[ks], S.oacc[0]);
    S.oacc[1] = mfma32(F.v1[ks], pf[ks], S.oacc[1]);
  }
  __builtin_amdgcn_s_setprio(0);
}

__device__ __forceinline__ void store_o(const QTile& S, bf16* orow, int hi) {
  float rinv = 1.f / S.l;
  #pragma unroll
  for (int dm = 0; dm < 2; ++dm) {
    #pragma unroll
    for (int g = 0; g < 4; ++g) {
      bf16x4 st;
      #pragma unroll
      for (int i = 0; i < 4; ++i) st[i] = (bf16)(S.oacc[dm][4 * g + i] * rinv);
      *(bf16x4*)(orow + dm * 32 + g * 8 + hi * 4) = st;
    }
  }
}

// grid: 4096 x 128 threads. bh = bid&63 (bid&7 pins bh's blocks to one XCD);
// u = 63-(bid>>6) -> longest q-units dispatched first.
__launch_bounds__(128, 2)
__global__ void attn_kernel(const bf16* __restrict__ Q, const bf16* __restrict__ K,
                            const bf16* __restrict__ Vt, bf16* __restrict__ Oc) {
  __shared__ float obuf[32][64];      // wave1 O^T regs, [reg r][lane]
  __shared__ float mlbuf[2][64];
  const int tid = threadIdx.x, lane = tid & 63, w = tid >> 6;
  const int hi = lane >> 5, ln = lane & 31;
  const int bid = blockIdx.x;
  const int bh = bid & 63;
  const int u  = 63 - (bid >> 6);
  const int qu = u * 32;
  const int qg = qu + ln;
  const int Tu = (u >> 1) + 1;
  const bf16* Kb = K  + (size_t)bh * (S_ * D_);
  const bf16* Vb = Vt + (size_t)bh * (D_ * S_);

  QTile S;
  init_q(S, Q + ((size_t)bh * S_ + qg) * D_, hi);

  // kv loop: tiles t = w, w+2, w+4, ...  Register double-buffer fA/fB (static names).
  KVf fA, fB;
  int t = w;
  if (t < Tu) load_kv(fA, Kb, Vb, t * 64, hi, ln);
  bool useA = true;
  for (; t < Tu; t += 2) {
    const int tn = t + 2;
    if (useA) {
      if (tn < Tu) load_kv(fB, Kb, Vb, tn * 64, hi, ln);
      compute_kv(S, fA, t * 64, qu, qg, hi, ln);
    } else {
      if (tn < Tu) load_kv(fA, Kb, Vb, tn * 64, hi, ln);
      compute_kv(S, fB, t * 64, qu, qg, hi, ln);
    }
    useA = !useA;
  }

  // merge the two parity partials (wave1 -> LDS, wave0 combines & stores)
  if (w == 1) {
    mlbuf[0][lane] = S.m; mlbuf[1][lane] = S.l;
    #pragma unroll
    for (int dm = 0; dm < 2; ++dm)
      #pragma unroll
      for (int r = 0; r < 16; ++r)
        obuf[dm * 16 + r][lane] = S.oacc[dm][r];
  }
  __syncthreads();
  if (w == 0) {
    float mB = mlbuf[0][lane], lB = mlbuf[1][lane];
    float mN = fmaxf(S.m, mB);
    float aA = exp2f(S.m - mN), aB = exp2f(mB - mN);
    S.l = S.l * aA + lB * aB;
    #pragma unroll
    for (int dm = 0; dm < 2; ++dm)
      #pragma unroll
      for (int r = 0; r < 16; ++r)
        S.oacc[dm][r] = S.oacc[dm][r] * aA + obuf[dm * 16 + r][lane] * aB;
    const int b = bh >> 4, h = bh & 15;
    store_o(S, Oc + ((size_t)(b * S_ + qg)) * E_ + h * D_, hi);
  }
}

// ---------- launcher ----------
extern "C" void kernel_launch(void* const* d_in, const int* in_sizes, int n_in,
                              void* d_out, int out_size, void* d_ws, size_t ws_size,
                              hipStream_t stream) {
  const float* x  = (const float*)d_in[0];
  const float* Wq = (const float*)d_in[1];
  const float* bq = (const float*)d_in[2];
  const float* Wk = (const float*)d_in[3];
  const float* bk = (const float*)d_in[4];
  const float* Wv = (const float*)d_in[5];
  const float* bv = (const float*)d_in[6];
  const float* Wo = (const float*)d_in[7];
  const float* bo = (const float*)d_in[8];
  float* out = (float*)d_out;

  uint8_t* ws = (uint8_t*)d_ws;
  bf16* Xbf   = (bf16*)(ws + 0);           // [M][K]; later reused as concat
  bf16* Wpack = (bf16*)(ws + 16777216);    // [3072][1024]
  bf16* Wot   = (bf16*)(ws + 23068672);    // [1024][1024]
  bf16* Qb    = (bf16*)(ws + 25165824);    // [B,H,S,D] (pre-scaled)
  bf16* Kb    = (bf16*)(ws + 41943040);
  bf16* Vb    = (bf16*)(ws + 58720256);
  bf16* Vtb   = (bf16*)(ws + 75497472);    // [B,H,D,S]
  bf16* Cc    = Xbf;

  cast_f32_bf16<<<2048, 256, 0, stream>>>(x,  Xbf, (M_ * K_) / 4);
  cast_f32_bf16<<<1024, 256, 0, stream>>>(Wo, Wot, (E_ * E_) / 4);
  pack_w_t<<<dim3(16, 48), 256, 0, stream>>>(Wq, Wk, Wv, Wpack);

  gemm_kernel<0><<<dim3(64 * 24), 256, 0, stream>>>(Xbf, Wpack, 3072, bq, bk, bv,
                                                    Qb, Kb, Vb, nullptr);
  transpose_v<<<dim3(S_ / 64, B_ * H_), 256, 0, stream>>>(Vb, Vtb);

  attn_kernel<<<4096, 128, 0, stream>>>(Qb, Kb, Vtb, Cc);

  gemm_kernel<1><<<dim3(64 * 8), 256, 0, stream>>>(Cc, Wot, 1024, bo, nullptr, nullptr,
                                                   nullptr, nullptr, nullptr, out);
}

// Round 8
// 199.888 us; speedup vs baseline: 1.9570x; 1.9570x over previous
//
#include <hip/hip_runtime.h>
#include <stdint.h>
#include <stddef.h>

// ---------- types ----------
typedef __bf16 bf16;
typedef __bf16 bf16x8 __attribute__((ext_vector_type(8)));
typedef __bf16 bf16x4 __attribute__((ext_vector_type(4)));
typedef float  f32x4  __attribute__((ext_vector_type(4)));
typedef float  f32x16 __attribute__((ext_vector_type(16)));
typedef unsigned short ush;
typedef ush ush8 __attribute__((ext_vector_type(8)));
typedef unsigned int uint;

// ---------- problem sizes ----------
#define B_  4
#define S_  2048
#define E_  1024
#define H_  16
#define D_  64
#define M_  (B_*S_)      // 8192 rows
#define K_  E_           // 1024 reduction
// 0.125 (1/sqrt(D)) * log2(e): QKV epilogue folds this into Q -> softmax in exp2 domain
#define QSCALE 0.18033688011112042f

// ---------- helpers ----------
__device__ __forceinline__ void gload_lds16(const void* g, void* l) {
  __builtin_amdgcn_global_load_lds((const __attribute__((address_space(1))) void*)g,
                                   (__attribute__((address_space(3))) void*)l, 16, 0, 0);
}
__device__ __forceinline__ f32x4 mfma16(bf16x8 a, bf16x8 b, f32x4 c) {
  return __builtin_amdgcn_mfma_f32_16x16x32_bf16(a, b, c, 0, 0, 0);
}
__device__ __forceinline__ f32x16 mfma32(bf16x8 a, bf16x8 b, f32x16 c) {
  return __builtin_amdgcn_mfma_f32_32x32x16_bf16(a, b, c, 0, 0, 0);
}
__device__ __forceinline__ int swz4(int row, int ch) { return ch ^ ((row >> 1) & 3); }
__device__ __forceinline__ uint cvtpk(float lo, float hi) {
  uint r;
  asm("v_cvt_pk_bf16_f32 %0, %1, %2" : "=v"(r) : "v"(lo), "v"(hi));
  return r;
}

// ---------- prep kernels ----------
__global__ void cast_f32_bf16(const float* __restrict__ src, bf16* __restrict__ dst, int n4) {
  int idx = blockIdx.x * blockDim.x + threadIdx.x;
  int stride = gridDim.x * blockDim.x;
  for (int i = idx; i < n4; i += stride) {
    float4 v = ((const float4*)src)[i];
    union { bf16 b[4]; ushort4 u; } cv;
    cv.b[0] = (bf16)v.x; cv.b[1] = (bf16)v.y; cv.b[2] = (bf16)v.z; cv.b[3] = (bf16)v.w;
    ((ushort4*)dst)[i] = cv.u;
  }
}

// pack Wq|Wk|Wv [H,E,D] -> Wp[n][e], n = which*1024 + h*64 + d. LDS-tiled transpose.
__global__ void pack_w_t(const float* __restrict__ Wq, const float* __restrict__ Wk,
                         const float* __restrict__ Wv, bf16* __restrict__ Wp) {
  __shared__ float t[64][65];
  const int tid = threadIdx.x;
  const int wh = blockIdx.y;          // 0..47
  const int which = wh >> 4, h = wh & 15;
  const int e0 = blockIdx.x << 6;
  const float* src = (which == 0) ? Wq : (which == 1 ? Wk : Wv);
  src += (size_t)h * (E_ * D_);       // [E][D] for this head
  #pragma unroll
  for (int i = 0; i < 4; ++i) {
    int fi = tid + 256 * i;
    int e = fi >> 4, c = fi & 15;
    float4 v = *(const float4*)(src + (size_t)(e0 + e) * D_ + c * 4);
    t[c * 4 + 0][e] = v.x; t[c * 4 + 1][e] = v.y;
    t[c * 4 + 2][e] = v.z; t[c * 4 + 3][e] = v.w;
  }
  __syncthreads();
  #pragma unroll
  for (int i = 0; i < 2; ++i) {
    int cid = tid + 256 * i;
    int d = cid >> 3, cc = cid & 7;
    ush8 o;
    #pragma unroll
    for (int j = 0; j < 8; ++j) {
      union { bf16 b; ush u; } cv; cv.b = (bf16)t[d][cc * 8 + j]; o[j] = cv.u;
    }
    *(ush8*)(Wp + ((size_t)which * 1024 + h * 64 + d) * K_ + e0 + cc * 8) = o;
  }
}

// ---------- GEMM: C[M][N] = A[M][K] * Bm[N][K]^T ----------
// MODE 0: scatter bf16 into Q [B,H,S,D] (pre-scaled), K [B,H,S,D], V -> Vt [B,H,D,S].
// MODE 1: fp32 out (+bias).
template <int MODE>
__launch_bounds__(256, 2)
__global__ void gemm_kernel(const bf16* __restrict__ A, const bf16* __restrict__ Bm,
                            int Ntot,
                            const float* __restrict__ bias0, const float* __restrict__ bias1,
                            const float* __restrict__ bias2,
                            bf16* __restrict__ Qo, bf16* __restrict__ Ko, bf16* __restrict__ Vto,
                            float* __restrict__ Fo) {
  __shared__ __align__(16) bf16 lds_a[2][128 * 32];
  __shared__ __align__(16) bf16 lds_b[2][128 * 32];
  const int tid = threadIdx.x;
  const int lane = tid & 63;
  const int w = tid >> 6;
  const int wr = w >> 1, wc = w & 1;
  const int nblk = Ntot >> 7;
  // bijective XCD-chunk swizzle (nwg % 8 == 0): each XCD gets a contiguous chunk
  const int qch = gridDim.x >> 3;
  const int swz = (blockIdx.x & 7) * qch + (blockIdx.x >> 3);
  const int mt = swz / nblk, nt = swz % nblk;
  const int m0 = mt << 7, n0 = nt << 7;

  f32x4 acc[4][4] = {};

  auto stage = [&](int buf, int kt) {
    #pragma unroll
    for (int i = 0; i < 2; ++i) {
      int cb = (w * 2 + i) * 64;
      int cid = cb + lane;
      int row = cid >> 2, cir = cid & 3;
      int lch = swz4(row, cir);
      const bf16* ga = A  + (size_t)(m0 + row) * K_ + kt * 32 + lch * 8;
      const bf16* gb = Bm + (size_t)(n0 + row) * K_ + kt * 32 + lch * 8;
      gload_lds16(ga, &lds_a[buf][cb * 8]);
      gload_lds16(gb, &lds_b[buf][cb * 8]);
    }
  };

  const int NT = K_ / 32;
  stage(0, 0);
  for (int kt = 0; kt < NT; ++kt) {
    if (kt + 1 < NT) stage((kt + 1) & 1, kt + 1);
    __syncthreads();
    const bf16x8* pa = (const bf16x8*)&lds_a[kt & 1][0];
    const bf16x8* pb = (const bf16x8*)&lds_b[kt & 1][0];
    bf16x8 af[4], bfr[4];
    #pragma unroll
    for (int mb = 0; mb < 4; ++mb) {
      int row = wr * 64 + mb * 16 + (lane & 15);
      af[mb] = pa[row * 4 + swz4(row, lane >> 4)];
    }
    #pragma unroll
    for (int nb = 0; nb < 4; ++nb) {
      int row = wc * 64 + nb * 16 + (lane & 15);
      bfr[nb] = pb[row * 4 + swz4(row, lane >> 4)];
    }
    #pragma unroll
    for (int mb = 0; mb < 4; ++mb)
      #pragma unroll
      for (int nb = 0; nb < 4; ++nb)
        acc[mb][nb] = mfma16(af[mb], bfr[nb], acc[mb][nb]);
    __syncthreads();
  }

  #pragma unroll
  for (int mb = 0; mb < 4; ++mb) {
    #pragma unroll
    for (int nb = 0; nb < 4; ++nb) {
      const int ni  = n0 + wc * 64 + nb * 16 + (lane & 15);
      const int mi0 = m0 + wr * 64 + mb * 16 + (lane >> 4) * 4;
      if (MODE == 0) {
        const int which = ni >> 10;          // uniform within the 16-lane group
        const int col = ni & 1023;
        const float* bp = (which == 0) ? bias0 : (which == 1 ? bias1 : bias2);
        const float bv = bp[col];
        const int hh = col >> 6, d = col & 63;
        const int b = mi0 >> 11, s0r = mi0 & 2047;
        if (which == 2) {                    // V: write transposed Vt[B,H,D,S]
          bf16x4 st;
          #pragma unroll
          for (int r = 0; r < 4; ++r) st[r] = (bf16)(acc[mb][nb][r] + bv);
          *(bf16x4*)(Vto + ((size_t)((b * H_ + hh) * D_ + d)) * S_ + s0r) = st;
        } else {
          bf16* dst = (which == 0) ? Qo : Ko;
          const float sc = (which == 0) ? QSCALE : 1.f;
          #pragma unroll
          for (int r = 0; r < 4; ++r)
            dst[(((size_t)(b * H_ + hh)) * S_ + (s0r + r)) * D_ + d] =
                (bf16)((acc[mb][nb][r] + bv) * sc);
        }
      } else {
        #pragma unroll
        for (int r = 0; r < 4; ++r)
          Fo[(size_t)(mi0 + r) * E_ + ni] = acc[mb][nb][r] + bias0[ni];
      }
    }
  }
}

// ---------- flash attention (causal), swapped-QK^T 32x32, paired q-tiles + kv-split ----------
// S^T = mfma(K, Q): lane owns q = ln; kv regs crow(r,hi)=(r&3)+8*(r>>2)+4*hi.
// O^T = mfma(Vt, P^T): col = q = ln -> softmax state fully lane-local.
struct QTile {
  bf16x8 qf[4];
  f32x16 oacc[2];
  float m, l;
};

__device__ __forceinline__ void init_q(QTile& S, const bf16* qrow, int hi) {
  #pragma unroll
  for (int kc = 0; kc < 4; ++kc)
    S.qf[kc] = *(const bf16x8*)(qrow + (2 * kc + hi) * 8);
  #pragma unroll
  for (int r = 0; r < 16; ++r) { S.oacc[0][r] = 0.f; S.oacc[1][r] = 0.f; }
  S.m = -1e30f; S.l = 0.f;
}

__device__ __forceinline__ void tile_step(QTile& S, const bf16* klds, const bf16* vlds,
                                          int kv0, int qb_, int qg_, int hi, int ln) {
  if (kv0 > qb_ + 31) return;   // fully masked for this wave (barriers are outside)
  f32x16 s0 = {}, s1 = {};
  #pragma unroll
  for (int kc = 0; kc < 4; ++kc) {
    int ch = (2 * kc + hi) ^ (ln & 7);
    bf16x8 k0 = *(const bf16x8*)&klds[ln * 64 + ch * 8];
    bf16x8 k1 = *(const bf16x8*)&klds[(32 + ln) * 64 + ch * 8];
    s0 = mfma32(k0, S.qf[kc], s0);
    s1 = mfma32(k1, S.qf[kc], s1);
  }
  if (kv0 + 63 > qb_) {   // causal mask (only the diagonal-touching tile)
    #pragma unroll
    for (int r = 0; r < 16; ++r) {
      int crow = (r & 3) + 8 * (r >> 2) + 4 * hi;
      if (kv0 + crow > qg_)      s0[r] = -1e30f;
      if (kv0 + 32 + crow > qg_) s1[r] = -1e30f;
    }
  }
  float mt_ = s0[0];
  #pragma unroll
  for (int r = 1; r < 16; ++r) mt_ = fmaxf(mt_, s0[r]);
  #pragma unroll
  for (int r = 0; r < 16; ++r) mt_ = fmaxf(mt_, s1[r]);
  mt_ = fmaxf(mt_, __shfl_xor(mt_, 32, 64));
  bool resc = mt_ > S.m + 8.f;          // defer-max (T13)
  float mnew = resc ? mt_ : S.m;
  float alpha = resc ? exp2f(S.m - mnew) : 1.f;
  S.m = mnew;
  float rs = 0.f;
  #pragma unroll
  for (int r = 0; r < 16; ++r) { float p = exp2f(s0[r] - mnew); s0[r] = p; rs += p; }
  #pragma unroll
  for (int r = 0; r < 16; ++r) { float p = exp2f(s1[r] - mnew); s1[r] = p; rs += p; }
  rs += __shfl_xor(rs, 32, 64);
  S.l = S.l * alpha + rs;
  if (__any(resc)) {
    #pragma unroll
    for (int r = 0; r < 16; ++r) { S.oacc[0][r] *= alpha; S.oacc[1][r] *= alpha; }
  }
  // pack P -> PV B-fragments (cvt_pk + permlane32_swap, T12)
  bf16x8 pf[4];
  #pragma unroll
  for (int mtl = 0; mtl < 2; ++mtl) {
    #pragma unroll
    for (int c = 0; c < 2; ++c) {
      const f32x16& p = mtl ? s1 : s0;
      uint wa = cvtpk(p[8 * c + 0], p[8 * c + 1]);
      uint wb = cvtpk(p[8 * c + 2], p[8 * c + 3]);
      uint wcx = cvtpk(p[8 * c + 4], p[8 * c + 5]);
      uint wd = cvtpk(p[8 * c + 6], p[8 * c + 7]);
      asm("v_permlane32_swap_b32 %0, %1" : "+v"(wa), "+v"(wcx));
      asm("v_permlane32_swap_b32 %0, %1" : "+v"(wb), "+v"(wd));
      union { uint u[4]; bf16x8 v; } cvt;
      cvt.u[0] = wa; cvt.u[1] = wb; cvt.u[2] = wcx; cvt.u[3] = wd;
      pf[mtl * 2 + c] = cvt.v;
    }
  }
  #pragma unroll
  for (int dm = 0; dm < 2; ++dm) {
    #pragma unroll
    for (int ks = 0; ks < 4; ++ks) {
      int row = dm * 32 + ln;
      int ch = (2 * ks + hi) ^ (ln & 7);
      bf16x8 vf = *(const bf16x8*)&vlds[row * 64 + ch * 8];
      S.oacc[dm] = mfma32(vf, pf[ks], S.oacc[dm]);
    }
  }
}

__device__ __forceinline__ void store_o(const QTile& S, bf16* orow, int hi) {
  float rinv = 1.f / S.l;
  #pragma unroll
  for (int dm = 0; dm < 2; ++dm) {
    #pragma unroll
    for (int g = 0; g < 4; ++g) {
      bf16x4 st;
      #pragma unroll
      for (int i = 0; i < 4; ++i) st[i] = (bf16)(S.oacc[dm][4 * g + i] * rinv);
      *(bf16x4*)(orow + dm * 32 + g * 8 + hi * 4) = st;
    }
  }
}

__device__ __forceinline__ void store_part(const QTile& S, bf16* prow, float* pml, int hi) {
  #pragma unroll
  for (int dm = 0; dm < 2; ++dm) {
    #pragma unroll
    for (int g = 0; g < 4; ++g) {
      bf16x4 st;
      #pragma unroll
      for (int i = 0; i < 4; ++i) st[i] = (bf16)S.oacc[dm][4 * g + i];
      *(bf16x4*)(prow + dm * 32 + g * 8 + hi * 4) = st;
    }
  }
  if (hi == 0) { pml[0] = S.m; pml[1] = S.l; }
}

// grid: 512*nh blocks x 256 threads. bh = bid&63 (bid&7 pins bh to one XCD).
// rest = bid>>6: x = rest&7 (pair {x, 15-x}), h = rest>>3 (kv half when nh==2).
// Per block: q-tile x kv-tiles [h*(x+1),(h+1)*(x+1)) + q-tile 15-x kv-tiles
// [h*(16-x),(h+1)*(16-x)) -> exactly 17 tile-steps for every block when nh==2.
__launch_bounds__(256, 2)
__global__ void attn_kernel(const bf16* __restrict__ Q, const bf16* __restrict__ K,
                            const bf16* __restrict__ Vt, bf16* __restrict__ Cc,
                            bf16* __restrict__ Po, float* __restrict__ Pml, int nh) {
  __shared__ __align__(16) bf16 k_lds[2][64 * 64];
  __shared__ __align__(16) bf16 v_lds[2][64 * 64];
  const int tid = threadIdx.x, lane = tid & 63, w = tid >> 6;
  const int hi = lane >> 5, ln = lane & 31;
  const int bid = blockIdx.x;
  const int bh = bid & 63;
  const int rest = bid >> 6;
  const int x = rest & 7;
  const int h = (nh == 2) ? (rest >> 3) : 0;
  const int jta = x, jtb = 15 - x;
  const int lenA = (2 * x + 2) / nh, lenB = (32 - 2 * x) / nh;
  const int ta0 = h * lenA, ta1 = ta0 + lenA;
  const int tb0 = h * lenB, tb1 = tb0 + lenB;
  const bf16* Kb = K  + (size_t)bh * (S_ * D_);
  const bf16* Vb = Vt + (size_t)bh * (D_ * S_);

  auto stage = [&](int buf, int t) {
    const int kv0 = t << 6;
    #pragma unroll
    for (int i = 0; i < 2; ++i) {
      int cb = (w * 2 + i) * 64;
      int cid = cb + lane;
      int row = cid >> 3, cir = cid & 7;
      int lch = cir ^ (row & 7);   // pre-swizzle source; LDS stays linear
      gload_lds16(Kb + (size_t)(kv0 + row) * D_ + lch * 8, &k_lds[buf][cb * 8]);
      gload_lds16(Vb + (size_t)row * S_ + kv0 + lch * 8, &v_lds[buf][cb * 8]);
    }
  };

  QTile SA, SB;
  const int sA = jta * 128 + w * 32 + ln, sB = jtb * 128 + w * 32 + ln;
  init_q(SA, Q + ((size_t)bh * S_ + sA) * D_, hi);
  init_q(SB, Q + ((size_t)bh * S_ + sB) * D_, hi);

  {  // sub-loop A
    const int qb_ = jta * 128 + w * 32, qg_ = qb_ + ln;
    stage(0, ta0);
    __syncthreads();
    for (int t = ta0; t < ta1; ++t) {
      int cur = (t - ta0) & 1;
      if (t + 1 < ta1) stage(cur ^ 1, t + 1);
      tile_step(SA, k_lds[cur], v_lds[cur], t * 64, qb_, qg_, hi, ln);
      __syncthreads();
    }
  }
  {  // sub-loop B
    const int qb_ = jtb * 128 + w * 32, qg_ = qb_ + ln;
    stage(0, tb0);
    __syncthreads();
    for (int t = tb0; t < tb1; ++t) {
      int cur = (t - tb0) & 1;
      if (t + 1 < tb1) stage(cur ^ 1, t + 1);
      tile_step(SB, k_lds[cur], v_lds[cur], t * 64, qb_, qg_, hi, ln);
      __syncthreads();
    }
  }

  if (nh == 2) {
    size_t ra = (size_t)(h * 64 + bh) * 2048 + sA;
    size_t rb = (size_t)(h * 64 + bh) * 2048 + sB;
    store_part(SA, Po + ra * 64, Pml + ra * 2, hi);
    store_part(SB, Po + rb * 64, Pml + rb * 2, hi);
  } else {
    const int b = bh >> 4, hh = bh & 15;
    store_o(SA, Cc + ((size_t)(b * S_ + sA)) * E_ + hh * D_, hi);
    store_o(SB, Cc + ((size_t)(b * S_ + sB)) * E_ + hh * D_, hi);
  }
}

// merge the two kv-half partials -> concat bf16 [B,S,H*D]
__global__ void attn_merge(const bf16* __restrict__ Po, const float* __restrict__ Pml,
                           bf16* __restrict__ Cc) {
  const int idx = blockIdx.x * 256 + threadIdx.x;     // 1,048,576 threads
  const int rg = idx >> 3, oct = idx & 7;
  const int bh = rg >> 11, s = rg & 2047;
  const size_t r0 = (size_t)bh * 2048 + s;
  const size_t r1 = (size_t)(64 + bh) * 2048 + s;
  const float m0 = Pml[r0 * 2], l0 = Pml[r0 * 2 + 1];
  const float m1 = Pml[r1 * 2], l1 = Pml[r1 * 2 + 1];
  const float mx = fmaxf(m0, m1);
  const float a0 = exp2f(m0 - mx), a1 = exp2f(m1 - mx);
  const float rl = 1.f / (l0 * a0 + l1 * a1);
  const bf16x8 v0 = *(const bf16x8*)(Po + r0 * 64 + oct * 8);
  const bf16x8 v1 = *(const bf16x8*)(Po + r1 * 64 + oct * 8);
  bf16x8 o;
  #pragma unroll
  for (int j = 0; j < 8; ++j)
    o[j] = (bf16)(((float)v0[j] * a0 + (float)v1[j] * a1) * rl);
  const int b = bh >> 4, hh = bh & 15;
  *(bf16x8*)(Cc + ((size_t)(b * S_ + s)) * E_ + hh * D_ + oct * 8) = o;
}

// ---------- launcher ----------
extern "C" void kernel_launch(void* const* d_in, const int* in_sizes, int n_in,
                              void* d_out, int out_size, void* d_ws, size_t ws_size,
                              hipStream_t stream) {
  const float* x  = (const float*)d_in[0];
  const float* Wq = (const float*)d_in[1];
  const float* bq = (const float*)d_in[2];
  const float* Wk = (const float*)d_in[3];
  const float* bk = (const float*)d_in[4];
  const float* Wv = (const float*)d_in[5];
  const float* bv = (const float*)d_in[6];
  const float* Wo = (const float*)d_in[7];
  const float* bo = (const float*)d_in[8];
  float* out = (float*)d_out;

  uint8_t* ws = (uint8_t*)d_ws;
  bf16* Xbf   = (bf16*)(ws + 0);           // [M][K]; later reused as concat
  bf16* Wpack = (bf16*)(ws + 16777216);    // [3072][1024]
  bf16* Wot   = (bf16*)(ws + 23068672);    // [1024][1024]
  bf16* Qb    = (bf16*)(ws + 25165824);    // [B,H,S,D] (pre-scaled)
  bf16* Kb    = (bf16*)(ws + 41943040);    // [B,H,S,D]
  bf16* Vtb   = (bf16*)(ws + 75497472);    // [B,H,D,S] (written by GEMM epilogue)
  bf16* Cc    = Xbf;
  // kv-split partials (used only if ws is big enough)
  bf16*  Po  = (bf16*)(ws + 92274688);     // [2][64][2048][64] bf16 = 33.5 MB
  float* Pml = (float*)(ws + 125829120);   // [2][64][2048][2]  f32  = 2.1 MB
  const bool split = (ws_size >= 127926272ull);
  const int nh = split ? 2 : 1;

  cast_f32_bf16<<<2048, 256, 0, stream>>>(x,  Xbf, (M_ * K_) / 4);
  cast_f32_bf16<<<1024, 256, 0, stream>>>(Wo, Wot, (E_ * E_) / 4);
  pack_w_t<<<dim3(16, 48), 256, 0, stream>>>(Wq, Wk, Wv, Wpack);

  gemm_kernel<0><<<dim3(64 * 24), 256, 0, stream>>>(Xbf, Wpack, 3072, bq, bk, bv,
                                                    Qb, Kb, Vtb, nullptr);

  attn_kernel<<<dim3(512 * nh), 256, 0, stream>>>(Qb, Kb, Vtb, Cc, Po, Pml, nh);
  if (split) attn_merge<<<dim3(4096), 256, 0, stream>>>(Po, Pml, Cc);

  gemm_kernel<1><<<dim3(64 * 8), 256, 0, stream>>>(Cc, Wot, 1024, bo, nullptr, nullptr,
                                                   nullptr, nullptr, nullptr, out);
}

// Round 10
// 189.333 us; speedup vs baseline: 2.0661x; 1.0558x over previous
//
#include <hip/hip_runtime.h>
#include <stdint.h>
#include <stddef.h>

// ---------- types ----------
typedef __bf16 bf16;
typedef __bf16 bf16x8 __attribute__((ext_vector_type(8)));
typedef __bf16 bf16x4 __attribute__((ext_vector_type(4)));
typedef float  f32x4  __attribute__((ext_vector_type(4)));
typedef float  f32x16 __attribute__((ext_vector_type(16)));
typedef unsigned short ush;
typedef ush ush8 __attribute__((ext_vector_type(8)));
typedef unsigned int uint;

// ---------- problem sizes ----------
#define B_  4
#define S_  2048
#define E_  1024
#define H_  16
#define D_  64
#define M_  (B_*S_)      // 8192 rows
#define K_  E_           // 1024 reduction
// 0.125 (1/sqrt(D)) * log2(e): QKV epilogue folds this into Q -> softmax in exp2 domain
#define QSCALE 0.18033688011112042f

// ---------- helpers ----------
__device__ __forceinline__ void gload_lds16(const void* g, void* l) {
  __builtin_amdgcn_global_load_lds((const __attribute__((address_space(1))) void*)g,
                                   (__attribute__((address_space(3))) void*)l, 16, 0, 0);
}
__device__ __forceinline__ f32x4 mfma16(bf16x8 a, bf16x8 b, f32x4 c) {
  return __builtin_amdgcn_mfma_f32_16x16x32_bf16(a, b, c, 0, 0, 0);
}
__device__ __forceinline__ f32x16 mfma32(bf16x8 a, bf16x8 b, f32x16 c) {
  return __builtin_amdgcn_mfma_f32_32x32x16_bf16(a, b, c, 0, 0, 0);
}
__device__ __forceinline__ int swz4(int row, int ch) { return ch ^ ((row >> 1) & 3); }
__device__ __forceinline__ uint cvtpk(float lo, float hi) {
  uint r;
  asm("v_cvt_pk_bf16_f32 %0, %1, %2" : "=v"(r) : "v"(lo), "v"(hi));
  return r;
}

// ---------- prep kernels ----------
__global__ void cast_f32_bf16(const float* __restrict__ src, bf16* __restrict__ dst, int n4) {
  int idx = blockIdx.x * blockDim.x + threadIdx.x;
  int stride = gridDim.x * blockDim.x;
  for (int i = idx; i < n4; i += stride) {
    float4 v = ((const float4*)src)[i];
    union { bf16 b[4]; ushort4 u; } cv;
    cv.b[0] = (bf16)v.x; cv.b[1] = (bf16)v.y; cv.b[2] = (bf16)v.z; cv.b[3] = (bf16)v.w;
    ((ushort4*)dst)[i] = cv.u;
  }
}

// pack Wq|Wk|Wv [H,E,D] -> Wp[n][e], n = which*1024 + h*64 + d. LDS-tiled transpose.
__global__ void pack_w_t(const float* __restrict__ Wq, const float* __restrict__ Wk,
                         const float* __restrict__ Wv, bf16* __restrict__ Wp) {
  __shared__ float t[64][65];
  const int tid = threadIdx.x;
  const int wh = blockIdx.y;          // 0..47
  const int which = wh >> 4, h = wh & 15;
  const int e0 = blockIdx.x << 6;
  const float* src = (which == 0) ? Wq : (which == 1 ? Wk : Wv);
  src += (size_t)h * (E_ * D_);       // [E][D] for this head
  #pragma unroll
  for (int i = 0; i < 4; ++i) {
    int fi = tid + 256 * i;
    int e = fi >> 4, c = fi & 15;
    float4 v = *(const float4*)(src + (size_t)(e0 + e) * D_ + c * 4);
    t[c * 4 + 0][e] = v.x; t[c * 4 + 1][e] = v.y;
    t[c * 4 + 2][e] = v.z; t[c * 4 + 3][e] = v.w;
  }
  __syncthreads();
  #pragma unroll
  for (int i = 0; i < 2; ++i) {
    int cid = tid + 256 * i;
    int d = cid >> 3, cc = cid & 7;
    ush8 o;
    #pragma unroll
    for (int j = 0; j < 8; ++j) {
      union { bf16 b; ush u; } cv; cv.b = (bf16)t[d][cc * 8 + j]; o[j] = cv.u;
    }
    *(ush8*)(Wp + ((size_t)which * 1024 + h * 64 + d) * K_ + e0 + cc * 8) = o;
  }
}

// ---------- GEMM: C[M][N] = A[M][K] * Bm[N][K]^T ----------
// MODE 0: scatter bf16 into Q [B,H,S,D] (pre-scaled), K [B,H,S,D], V -> Vt [B,H,D,S].
// MODE 1: fp32 out (+bias).
template <int MODE>
__launch_bounds__(256, 3)
__global__ void gemm_kernel(const bf16* __restrict__ A, const bf16* __restrict__ Bm,
                            int Ntot,
                            const float* __restrict__ bias0, const float* __restrict__ bias1,
                            const float* __restrict__ bias2,
                            bf16* __restrict__ Qo, bf16* __restrict__ Ko, bf16* __restrict__ Vto,
                            float* __restrict__ Fo) {
  __shared__ __align__(16) bf16 lds_a[2][128 * 32];
  __shared__ __align__(16) bf16 lds_b[2][128 * 32];
  const int tid = threadIdx.x;
  const int lane = tid & 63;
  const int w = tid >> 6;
  const int wr = w >> 1, wc = w & 1;
  const int nblk = Ntot >> 7;
  // bijective XCD-chunk swizzle (nwg % 8 == 0): each XCD gets a contiguous chunk
  const int qch = gridDim.x >> 3;
  const int swz = (blockIdx.x & 7) * qch + (blockIdx.x >> 3);
  const int mt = swz / nblk, nt = swz % nblk;
  const int m0 = mt << 7, n0 = nt << 7;

  f32x4 acc[4][4] = {};

  auto stage = [&](int buf, int kt) {
    #pragma unroll
    for (int i = 0; i < 2; ++i) {
      int cb = (w * 2 + i) * 64;
      int cid = cb + lane;
      int row = cid >> 2, cir = cid & 3;
      int lch = swz4(row, cir);
      const bf16* ga = A  + (size_t)(m0 + row) * K_ + kt * 32 + lch * 8;
      const bf16* gb = Bm + (size_t)(n0 + row) * K_ + kt * 32 + lch * 8;
      gload_lds16(ga, &lds_a[buf][cb * 8]);
      gload_lds16(gb, &lds_b[buf][cb * 8]);
    }
  };

  const int NT = K_ / 32;
  stage(0, 0);
  for (int kt = 0; kt < NT; ++kt) {
    if (kt + 1 < NT) stage((kt + 1) & 1, kt + 1);
    __syncthreads();
    const bf16x8* pa = (const bf16x8*)&lds_a[kt & 1][0];
    const bf16x8* pb = (const bf16x8*)&lds_b[kt & 1][0];
    bf16x8 af[4], bfr[4];
    #pragma unroll
    for (int mb = 0; mb < 4; ++mb) {
      int row = wr * 64 + mb * 16 + (lane & 15);
      af[mb] = pa[row * 4 + swz4(row, lane >> 4)];
    }
    #pragma unroll
    for (int nb = 0; nb < 4; ++nb) {
      int row = wc * 64 + nb * 16 + (lane & 15);
      bfr[nb] = pb[row * 4 + swz4(row, lane >> 4)];
    }
    #pragma unroll
    for (int mb = 0; mb < 4; ++mb)
      #pragma unroll
      for (int nb = 0; nb < 4; ++nb)
        acc[mb][nb] = mfma16(af[mb], bfr[nb], acc[mb][nb]);
    __syncthreads();
  }

  #pragma unroll
  for (int mb = 0; mb < 4; ++mb) {
    #pragma unroll
    for (int nb = 0; nb < 4; ++nb) {
      const int ni  = n0 + wc * 64 + nb * 16 + (lane & 15);
      const int mi0 = m0 + wr * 64 + mb * 16 + (lane >> 4) * 4;
      if (MODE == 0) {
        const int which = ni >> 10;          // uniform within the 16-lane group
        const int col = ni & 1023;
        const float* bp = (which == 0) ? bias0 : (which == 1 ? bias1 : bias2);
        const float bv = bp[col];
        const int hh = col >> 6, d = col & 63;
        const int b = mi0 >> 11, s0r = mi0 & 2047;
        if (which == 2) {                    // V: write transposed Vt[B,H,D,S]
          bf16x4 st;
          #pragma unroll
          for (int r = 0; r < 4; ++r) st[r] = (bf16)(acc[mb][nb][r] + bv);
          *(bf16x4*)(Vto + ((size_t)((b * H_ + hh) * D_ + d)) * S_ + s0r) = st;
        } else {
          bf16* dst = (which == 0) ? Qo : Ko;
          const float sc = (which == 0) ? QSCALE : 1.f;
          #pragma unroll
          for (int r = 0; r < 4; ++r)
            dst[(((size_t)(b * H_ + hh)) * S_ + (s0r + r)) * D_ + d] =
                (bf16)((acc[mb][nb][r] + bv) * sc);
        }
      } else {
        #pragma unroll
        for (int r = 0; r < 4; ++r)
          Fo[(size_t)(mi0 + r) * E_ + ni] = acc[mb][nb][r] + bias0[ni];
      }
    }
  }
}

// ---------- flash attention (causal): swapped-QK^T 32x32, KVBLK=128 phases ----------
// S^T = mfma(K, Q): lane owns q = ln; kv regs crow(r,hi)=(r&3)+8*(r>>2)+4*hi.
// O^T = mfma(Vt, P^T): col = q = ln -> softmax state fully lane-local.
struct QTile {
  bf16x8 qf[4];
  f32x16 oacc[2];
  float m, l;
};

__device__ __forceinline__ void init_q(QTile& S, const bf16* qrow, int hi) {
  #pragma unroll
  for (int kc = 0; kc < 4; ++kc)
    S.qf[kc] = *(const bf16x8*)(qrow + (2 * kc + hi) * 8);
  #pragma unroll
  for (int r = 0; r < 16; ++r) { S.oacc[0][r] = 0.f; S.oacc[1][r] = 0.f; }
  S.m = -1e30f; S.l = 0.f;
}

// klds: [128][64] (8 chunks/row, swz ch^(row&7));  vlds: [64][128] (16 chunks/row,
// swz ch^(row&15)). sub selects the 64-kv half; kv0 is the absolute 64-tile base.
__device__ __forceinline__ void tile_step(QTile& S, const bf16* klds, const bf16* vlds,
                                          int sub, int kv0, int qb_, int qg_, int hi, int ln) {
  if (kv0 > qb_ + 31) return;   // fully masked for this wave (no barriers inside)
  const bf16* kbase = klds + sub * (64 * 64);
  f32x16 s0 = {}, s1 = {};
  #pragma unroll
  for (int kc = 0; kc < 4; ++kc) {
    int ch = (2 * kc + hi) ^ (ln & 7);
    bf16x8 k0 = *(const bf16x8*)&kbase[ln * 64 + ch * 8];
    bf16x8 k1 = *(const bf16x8*)&kbase[(32 + ln) * 64 + ch * 8];
    s0 = mfma32(k0, S.qf[kc], s0);
    s1 = mfma32(k1, S.qf[kc], s1);
  }
  if (kv0 + 63 > qb_) {   // causal mask (only the diagonal-touching tile)
    #pragma unroll
    for (int r = 0; r < 16; ++r) {
      int crow = (r & 3) + 8 * (r >> 2) + 4 * hi;
      if (kv0 + crow > qg_)      s0[r] = -1e30f;
      if (kv0 + 32 + crow > qg_) s1[r] = -1e30f;
    }
  }
  float mt_ = s0[0];
  #pragma unroll
  for (int r = 1; r < 16; ++r) mt_ = fmaxf(mt_, s0[r]);
  #pragma unroll
  for (int r = 0; r < 16; ++r) mt_ = fmaxf(mt_, s1[r]);
  mt_ = fmaxf(mt_, __shfl_xor(mt_, 32, 64));
  bool resc = mt_ > S.m + 8.f;          // defer-max (T13)
  float mnew = resc ? mt_ : S.m;
  float alpha = resc ? exp2f(S.m - mnew) : 1.f;
  S.m = mnew;
  float rs = 0.f;
  #pragma unroll
  for (int r = 0; r < 16; ++r) { float p = exp2f(s0[r] - mnew); s0[r] = p; rs += p; }
  #pragma unroll
  for (int r = 0; r < 16; ++r) { float p = exp2f(s1[r] - mnew); s1[r] = p; rs += p; }
  rs += __shfl_xor(rs, 32, 64);
  S.l = S.l * alpha + rs;
  if (__any(resc)) {
    #pragma unroll
    for (int r = 0; r < 16; ++r) { S.oacc[0][r] *= alpha; S.oacc[1][r] *= alpha; }
  }
  // pack P -> PV B-fragments (cvt_pk + permlane32_swap, T12)
  bf16x8 pf[4];
  #pragma unroll
  for (int mtl = 0; mtl < 2; ++mtl) {
    #pragma unroll
    for (int c = 0; c < 2; ++c) {
      const f32x16& p = mtl ? s1 : s0;
      uint wa = cvtpk(p[8 * c + 0], p[8 * c + 1]);
      uint wb = cvtpk(p[8 * c + 2], p[8 * c + 3]);
      uint wcx = cvtpk(p[8 * c + 4], p[8 * c + 5]);
      uint wd = cvtpk(p[8 * c + 6], p[8 * c + 7]);
      asm("v_permlane32_swap_b32 %0, %1" : "+v"(wa), "+v"(wcx));
      asm("v_permlane32_swap_b32 %0, %1" : "+v"(wb), "+v"(wd));
      union { uint u[4]; bf16x8 v; } cvt;
      cvt.u[0] = wa; cvt.u[1] = wb; cvt.u[2] = wcx; cvt.u[3] = wd;
      pf[mtl * 2 + c] = cvt.v;
    }
  }
  #pragma unroll
  for (int dm = 0; dm < 2; ++dm) {
    #pragma unroll
    for (int ks = 0; ks < 4; ++ks) {
      int row = dm * 32 + ln;
      int cfull = sub * 8 + 2 * ks + hi;
      int ch = cfull ^ (ln & 15);
      bf16x8 vf = *(const bf16x8*)&vlds[row * 128 + ch * 8];
      S.oacc[dm] = mfma32(vf, pf[ks], S.oacc[dm]);
    }
  }
}

__device__ __forceinline__ void store_o(const QTile& S, bf16* orow, int hi) {
  float rinv = 1.f / S.l;
  #pragma unroll
  for (int dm = 0; dm < 2; ++dm) {
    #pragma unroll
    for (int g = 0; g < 4; ++g) {
      bf16x4 st;
      #pragma unroll
      for (int i = 0; i < 4; ++i) st[i] = (bf16)(S.oacc[dm][4 * g + i] * rinv);
      *(bf16x4*)(orow + dm * 32 + g * 8 + hi * 4) = st;
    }
  }
}

// grid: 512 x 256 threads. bh = bid&63 (bid&7 pins bh's 8 blocks to one XCD);
// x = bid>>6 -> q-tile pair {x, 15-x}. Phases of 2 kv-tiles: A needs x+1 phases,
// B needs 16-x -> uniform 17 phases (34 tiles) per block.
__launch_bounds__(256, 2)
__global__ void attn_kernel(const bf16* __restrict__ Q, const bf16* __restrict__ K,
                            const bf16* __restrict__ Vt, bf16* __restrict__ Cc) {
  __shared__ __align__(16) bf16 k_lds[2][128 * 64];   // [kv 128][d 64] swz8
  __shared__ __align__(16) bf16 v_lds[2][64 * 128];   // [d 64][kv 128] swz16
  const int tid = threadIdx.x, lane = tid & 63, w = tid >> 6;
  const int hi = lane >> 5, ln = lane & 31;
  const int bid = blockIdx.x;
  const int bh = bid & 63;
  const int x = bid >> 6;
  const int jta = x, jtb = 15 - x;
  const bf16* Kb = K  + (size_t)bh * (S_ * D_);
  const bf16* Vb = Vt + (size_t)bh * (D_ * S_);
  const int b = bh >> 4, hh = bh & 15;

  auto stage2 = [&](int buf, int ph) {   // stage kv [ph*128, ph*128+128)
    const int kv0 = ph << 7;
    #pragma unroll
    for (int i = 0; i < 4; ++i) {
      int cb = (w * 4 + i) * 64;
      int cid = cb + lane;
      int row = cid >> 3, cir = cid & 7;          // K: 128 rows x 8 chunks
      int lch = cir ^ (row & 7);
      gload_lds16(Kb + (size_t)(kv0 + row) * D_ + lch * 8, &k_lds[buf][cb * 8]);
      int rowv = cid >> 4, cirv = cid & 15;       // V: 64 rows x 16 chunks
      int lchv = cirv ^ (rowv & 15);
      gload_lds16(Vb + (size_t)rowv * S_ + kv0 + lchv * 8, &v_lds[buf][cb * 8]);
    }
  };

  {  // ---- q-tile A = x: phases [0, x+1) ----
    const int qb_ = jta * 128 + w * 32, qg_ = qb_ + ln;
    QTile SA;
    init_q(SA, Q + ((size_t)bh * S_ + qg_) * D_, hi);
    const int nph = x + 1;
    stage2(0, 0);
    __syncthreads();
    for (int ph = 0; ph < nph; ++ph) {
      int cur = ph & 1;
      if (ph + 1 < nph) stage2(cur ^ 1, ph + 1);
      tile_step(SA, k_lds[cur], v_lds[cur], 0, ph * 128,      qb_, qg_, hi, ln);
      tile_step(SA, k_lds[cur], v_lds[cur], 1, ph * 128 + 64, qb_, qg_, hi, ln);
      __syncthreads();
    }
    store_o(SA, Cc + ((size_t)(b * S_ + qg_)) * E_ + hh * D_, hi);
  }
  {  // ---- q-tile B = 15-x: phases [0, 16-x) ----
    const int qb_ = jtb * 128 + w * 32, qg_ = qb_ + ln;
    QTile SB;
    init_q(SB, Q + ((size_t)bh * S_ + qg_) * D_, hi);
    const int nph = 16 - x;
    stage2(0, 0);
    __syncthreads();
    for (int ph = 0; ph < nph; ++ph) {
      int cur = ph & 1;
      if (ph + 1 < nph) stage2(cur ^ 1, ph + 1);
      tile_step(SB, k_lds[cur], v_lds[cur], 0, ph * 128,      qb_, qg_, hi, ln);
      tile_step(SB, k_lds[cur], v_lds[cur], 1, ph * 128 + 64, qb_, qg_, hi, ln);
      __syncthreads();
    }
    store_o(SB, Cc + ((size_t)(b * S_ + qg_)) * E_ + hh * D_, hi);
  }
}

// ---------- launcher ----------
extern "C" void kernel_launch(void* const* d_in, const int* in_sizes, int n_in,
                              void* d_out, int out_size, void* d_ws, size_t ws_size,
                              hipStream_t stream) {
  const float* x  = (const float*)d_in[0];
  const float* Wq = (const float*)d_in[1];
  const float* bq = (const float*)d_in[2];
  const float* Wk = (const float*)d_in[3];
  const float* bk = (const float*)d_in[4];
  const float* Wv = (const float*)d_in[5];
  const float* bv = (const float*)d_in[6];
  const float* Wo = (const float*)d_in[7];
  const float* bo = (const float*)d_in[8];
  float* out = (float*)d_out;

  uint8_t* ws = (uint8_t*)d_ws;
  bf16* Xbf   = (bf16*)(ws + 0);           // [M][K]; later reused as concat
  bf16* Wpack = (bf16*)(ws + 16777216);    // [3072][1024]
  bf16* Wot   = (bf16*)(ws + 23068672);    // [1024][1024]
  bf16* Qb    = (bf16*)(ws + 25165824);    // [B,H,S,D] (pre-scaled)
  bf16* Kb    = (bf16*)(ws + 41943040);    // [B,H,S,D]
  bf16* Vtb   = (bf16*)(ws + 75497472);    // [B,H,D,S] (written by GEMM epilogue)
  bf16* Cc    = Xbf;

  cast_f32_bf16<<<2048, 256, 0, stream>>>(x,  Xbf, (M_ * K_) / 4);
  cast_f32_bf16<<<1024, 256, 0, stream>>>(Wo, Wot, (E_ * E_) / 4);
  pack_w_t<<<dim3(16, 48), 256, 0, stream>>>(Wq, Wk, Wv, Wpack);

  gemm_kernel<0><<<dim3(64 * 24), 256, 0, stream>>>(Xbf, Wpack, 3072, bq, bk, bv,
                                                    Qb, Kb, Vtb, nullptr);

  attn_kernel<<<dim3(512), 256, 0, stream>>>(Qb, Kb, Vtb, Cc);

  gemm_kernel<1><<<dim3(64 * 8), 256, 0, stream>>>(Cc, Wot, 1024, bo, nullptr, nullptr,
                                                   nullptr, nullptr, nullptr, out);
}